// Round 3
// baseline (583.593 us; speedup 1.0000x reference)
//
#include <hip/hip_runtime.h>
#include <hip/hip_bf16.h>
#include <cstdint>
#include <cstddef>

typedef __bf16 bf8_t __attribute__((ext_vector_type(8)));
typedef __bf16 bf4_t __attribute__((ext_vector_type(4)));
typedef float  f4_t  __attribute__((ext_vector_type(4)));

#define CC 768
#define NROWS 32768           // 8*4096
#define NTOT 25165824         // 32768*768

// ---------------- prep kernels ----------------

__global__ void make_cas(__bf16* __restrict__ cas) {
  int idx = blockIdx.x * 256 + threadIdx.x;      // 589824 total
  int i = idx / CC, j = idx - i * CC;
  int ij = (i * j) % CC;                          // exact arg reduction
  float ang = 6.283185307179586f * (float)ij / (float)CC;
  cas[idx] = (__bf16)(__cosf(ang) + __sinf(ang));
}

// pack weights into MFMA B-fragment order: frag[(kt*12+nt)*64 + lane][j]
__global__ void pack_w1(const float* __restrict__ w1, __bf16* __restrict__ w1f) {
  int f = blockIdx.x * 256 + threadIdx.x;        // < 8*36*64*8 = 147456
  int j = f & 7, lane = (f >> 3) & 63, rest = f >> 9;
  int nt = rest % 12, kt = (rest / 12) % 3, blk = rest / 36;
  int k = kt * 32 + (lane >> 4) * 8 + j;
  int o = nt * 16 + (lane & 15);
  float v = (o < 96) ? w1[(0 * 8 + blk) * 9216 + k * 96 + o]
                     : w1[(1 * 8 + blk) * 9216 + k * 96 + (o - 96)];
  w1f[f] = (__bf16)v;
}

__global__ void pack_w2(const float* __restrict__ w2, __bf16* __restrict__ w2f) {
  int f = blockIdx.x * 256 + threadIdx.x;        // < 8*72*64*8 = 294912
  int j = f & 7, lane = (f >> 3) & 63, rest = f >> 9;
  int nt = rest % 12, kt = (rest / 12) % 6, blk = rest / 72;
  int i = kt * 32 + (lane >> 4) * 8 + j;
  int o = nt * 16 + (lane & 15);
  float v;
  if (o < 96) v = (i < 96) ?  w2[(0 * 8 + blk) * 9216 + i * 96 + o]
                           : -w2[(1 * 8 + blk) * 9216 + (i - 96) * 96 + o];
  else        v = (i < 96) ?  w2[(1 * 8 + blk) * 9216 + i * 96 + (o - 96)]
                           :  w2[(0 * 8 + blk) * 9216 + (i - 96) * 96 + (o - 96)];
  w2f[f] = (__bf16)v;
}

// ---------------- main GEMM: register-prefetch pipelined K-loop ----------------
// MODE 0: A = float* (x, converted to bf16 during staging), C -> bf16 via LDS-staged
//         full-line stores.
// MODE 1: A = bf16* (Z), C = acc*scale + Xres -> float direct (full-line) stores.
// Loads go to REGISTERS (private) so __syncthreads() needs no vmcnt(0) drain; the
// global-load latency overlaps the current iteration's ds_read+MFMA.
template<int MODE>
__global__ __launch_bounds__(256) void gemm_cas(
    const void* __restrict__ Av, const __bf16* __restrict__ BT,
    __bf16* __restrict__ Cb, float* __restrict__ Cf,
    const float* __restrict__ Xres, float scale)
{
  __shared__ __align__(16) __bf16 smem[8192];   // 16 KB: sA=[0,4096) sB=[4096,8192)
  __bf16* sA = smem;
  __bf16* sB = smem + 4096;
  const int t = threadIdx.x, lane = t & 63, wid = t >> 6;
  const int wm = (wid >> 1) * 64, wn = (wid & 1) * 64;
  const int m0 = blockIdx.x * 128, n0 = blockIdx.y * 128;
  const int q = lane >> 4, r = lane & 15;
  const int srow = t >> 1, sh = (t & 1) * 16;   // staging: each thread 16 K-elts of one row

  const float*  Af = (const float*)Av;
  const __bf16* Ab = (const __bf16*)Av;

  float4 ra[4];   // MODE0 staging (16 f32)
  uint4  rab[2];  // MODE1 staging (16 bf16)
  uint4  rb[2];   // B staging (16 bf16)

  auto load_tiles = [&](int k0) {
    if (MODE == 0) {
      const float* p = Af + (size_t)(m0 + srow) * CC + k0 + sh;
      ra[0] = *(const float4*)(p);
      ra[1] = *(const float4*)(p + 4);
      ra[2] = *(const float4*)(p + 8);
      ra[3] = *(const float4*)(p + 12);
    } else {
      const __bf16* p = Ab + (size_t)(m0 + srow) * CC + k0 + sh;
      rab[0] = *(const uint4*)(p);
      rab[1] = *(const uint4*)(p + 8);
    }
    const __bf16* pb = BT + (size_t)(n0 + srow) * CC + k0 + sh;
    rb[0] = *(const uint4*)(pb);
    rb[1] = *(const uint4*)(pb + 8);
  };
  auto stage_tiles = [&]() {
    __bf16* da = sA + srow * 32 + sh;
    if (MODE == 0) {
      union { __bf16 h[16]; uint4 u[2]; } cv;
      const float* fp = (const float*)ra;
#pragma unroll
      for (int e = 0; e < 16; e++) cv.h[e] = (__bf16)fp[e];
      *(uint4*)(da) = cv.u[0];
      *(uint4*)(da + 8) = cv.u[1];
    } else {
      *(uint4*)(da) = rab[0];
      *(uint4*)(da + 8) = rab[1];
    }
    __bf16* db = sB + srow * 32 + sh;
    *(uint4*)(db) = rb[0];
    *(uint4*)(db + 8) = rb[1];
  };

  f4_t acc[4][4] = {};
  load_tiles(0);                       // prologue prefetch
  for (int k0 = 0; k0 < CC; k0 += 32) {
    __syncthreads();                   // prior iter's LDS reads done
    stage_tiles();
    __syncthreads();                   // staged data visible
    if (k0 + 32 < CC) load_tiles(k0 + 32);   // in flight during MFMA below
    bf8_t af[4], bfr[4];
#pragma unroll
    for (int i = 0; i < 4; i++)
      af[i] = *(const bf8_t*)(sA + (wm + i * 16 + r) * 32 + q * 8);
#pragma unroll
    for (int j = 0; j < 4; j++)
      bfr[j] = *(const bf8_t*)(sB + (wn + j * 16 + r) * 32 + q * 8);
#pragma unroll
    for (int i = 0; i < 4; i++)
#pragma unroll
      for (int j = 0; j < 4; j++)
        acc[i][j] = __builtin_amdgcn_mfma_f32_16x16x32_bf16(af[i], bfr[j], acc[i][j], 0, 0, 0);
  }

  // D layout: col = lane&15, row = (lane>>4)*4 + reg
  if (MODE == 1) {
#pragma unroll
    for (int i = 0; i < 4; i++)
#pragma unroll
      for (int j = 0; j < 4; j++) {
        int col = n0 + wn + j * 16 + r;
#pragma unroll
        for (int rr = 0; rr < 4; rr++) {
          int row = m0 + wm + i * 16 + q * 4 + rr;
          size_t off = (size_t)row * CC + col;
          Cf[off] = acc[i][j][rr] * scale + Xres[off];
        }
      }
  } else {
    // LDS-staged bf16 epilogue: two 64-row passes, full-line coalesced stores
    for (int h2 = 0; h2 < 2; h2++) {
      __syncthreads();
      if ((wid >> 1) == h2) {
#pragma unroll
        for (int i = 0; i < 4; i++)
#pragma unroll
          for (int j = 0; j < 4; j++)
#pragma unroll
            for (int rr = 0; rr < 4; rr++)
              smem[(i * 16 + q * 4 + rr) * 128 + wn + j * 16 + r] = (__bf16)acc[i][j][rr];
      }
      __syncthreads();
      const int lr = t >> 2, seg = t & 3;       // 64 rows x 4 segs of 64 B
      const uint4* src = (const uint4*)smem + lr * 16 + seg * 4;
      uint4* dst = (uint4*)(Cb + (size_t)(m0 + h2 * 64 + lr) * CC + n0) + seg * 4;
#pragma unroll
      for (int s = 0; s < 4; s++) dst[s] = src[s];
    }
  }
}

// ---------------- fused block-diagonal complex MLP + softshrink ----------------
__global__ __launch_bounds__(384, 3) void mlp_kernel(
    const __bf16* __restrict__ V,
    const __bf16* __restrict__ w1f, const __bf16* __restrict__ w2f,
    const float* __restrict__ b1, const float* __restrict__ b2,
    __bf16* __restrict__ Z)
{
  __shared__ __align__(16) __bf16 H[64 * 200];
  __shared__ __align__(16) __bf16 zl[64 * 96];
  const int t = threadIdx.x, lane = t & 63, w = t >> 6;   // w in 0..5
  const int blk = blockIdx.y;
  const int r0 = blockIdx.x * 128;
  const int q = lane >> 4, r = lane & 15;

  const __bf16* w1b = w1f + (size_t)blk * (36 * 64 * 8);
  const __bf16* w2b = w2f + (size_t)blk * (72 * 64 * 8);
  bf8_t w1r[3][2], w2r[6][2];
#pragma unroll
  for (int kt = 0; kt < 3; kt++)
#pragma unroll
    for (int j = 0; j < 2; j++)
      w1r[kt][j] = *(const bf8_t*)(w1b + ((size_t)(kt * 12 + 2 * w + j) * 64 + lane) * 8);
#pragma unroll
  for (int kt = 0; kt < 6; kt++) {
    w2r[kt][0] = *(const bf8_t*)(w2b + ((size_t)(kt * 12 + w) * 64 + lane) * 8);
    w2r[kt][1] = *(const bf8_t*)(w2b + ((size_t)(kt * 12 + w + 6) * 64 + lane) * 8);
  }
  float bb[2];
#pragma unroll
  for (int j = 0; j < 2; j++) {
    int c = (2 * w + j) * 16 + r;
    bb[j] = (c < 96) ? b1[blk * 96 + c] : b1[768 + blk * 96 + (c - 96)];
  }
  const float br = b2[blk * 96 + w * 16 + r];
  const float bi = b2[768 + blk * 96 + w * 16 + r];

  for (int h = 0; h < 2; h++) {
    const int rbase = r0 + h * 64;
#pragma unroll
    for (int rt = 0; rt < 4; rt++) {
      const __bf16* vp = V + (size_t)(rbase + rt * 16 + r) * CC + blk * 96 + q * 8;
      f4_t acc0 = {}, acc1 = {};
#pragma unroll
      for (int kt = 0; kt < 3; kt++) {
        bf8_t a = *(const bf8_t*)(vp + kt * 32);
        acc0 = __builtin_amdgcn_mfma_f32_16x16x32_bf16(a, w1r[kt][0], acc0, 0, 0, 0);
        acc1 = __builtin_amdgcn_mfma_f32_16x16x32_bf16(a, w1r[kt][1], acc1, 0, 0, 0);
      }
#pragma unroll
      for (int j = 0; j < 2; j++) {
        int c = (2 * w + j) * 16 + r;
        f4_t* ap = j ? &acc1 : &acc0;
#pragma unroll
        for (int rr = 0; rr < 4; rr++) {
          float v = (*ap)[rr] + bb[j];
          H[(rt * 16 + q * 4 + rr) * 200 + c] = (__bf16)(v > 0.f ? v : 0.f);
        }
      }
    }
    __syncthreads();
#pragma unroll
    for (int rt = 0; rt < 4; rt++) {
      f4_t ar = {}, ai = {};
#pragma unroll
      for (int kt = 0; kt < 6; kt++) {
        bf8_t a = *(const bf8_t*)(&H[(rt * 16 + r) * 200 + kt * 32 + q * 8]);
        ar = __builtin_amdgcn_mfma_f32_16x16x32_bf16(a, w2r[kt][0], ar, 0, 0, 0);
        ai = __builtin_amdgcn_mfma_f32_16x16x32_bf16(a, w2r[kt][1], ai, 0, 0, 0);
      }
#pragma unroll
      for (int rr = 0; rr < 4; rr++) {
        float yr = ar[rr] + br, yi = ai[rr] + bi;
        float sr = fabsf(yr) - 0.01f; sr = sr > 0.f ? copysignf(sr, yr) : 0.f;
        float si = fabsf(yi) - 0.01f; si = si > 0.f ? copysignf(si, yi) : 0.f;
        zl[(rt * 16 + q * 4 + rr) * 96 + w * 16 + r] = (__bf16)(sr - si);
      }
    }
    __syncthreads();
    {
      const uint32_t* zsrc = (const uint32_t*)zl;
      int cdw = t % 48, crow = t / 48;            // 8 rows per pass
#pragma unroll
      for (int it = 0; it < 8; it++) {
        int row = it * 8 + crow;
        uint32_t* dst = (uint32_t*)(Z + (size_t)(rbase + row) * CC + blk * 96);
        dst[cdw] = zsrc[row * 48 + cdw];
      }
    }
    __syncthreads();
  }
}

// ---------------- launch ----------------

extern "C" void kernel_launch(void* const* d_in, const int* in_sizes, int n_in,
                              void* d_out, int out_size, void* d_ws, size_t ws_size,
                              hipStream_t stream) {
  const float* x  = (const float*)d_in[0];
  const float* w1 = (const float*)d_in[1];
  const float* b1 = (const float*)d_in[2];
  const float* w2 = (const float*)d_in[3];
  const float* b2 = (const float*)d_in[4];
  float* out = (float*)d_out;

  char* ws = (char*)d_ws;
  size_t off = 0;
  auto alloc = [&](size_t bytes) {
    char* p = ws + off;
    off += (bytes + 255) & ~(size_t)255;
    return p;
  };
  __bf16* casb = (__bf16*)alloc((size_t)CC * CC * 2);        // 1.18 MB
  __bf16* w1f  = (__bf16*)alloc((size_t)8 * 36 * 64 * 8 * 2);
  __bf16* w2f  = (__bf16*)alloc((size_t)8 * 72 * 64 * 8 * 2);
  __bf16* vv   = (__bf16*)alloc((size_t)NTOT * 2);           // 50.3 MB
  __bf16* zb   = (__bf16*)alloc((size_t)NTOT * 2);           // 50.3 MB

  make_cas<<<2304, 256, 0, stream>>>(casb);
  pack_w1<<<576, 256, 0, stream>>>(w1, w1f);
  pack_w2<<<1152, 256, 0, stream>>>(w2, w2f);

  // V = bf16(x) @ CAS   (CAS symmetric => BT = CAS); f32->bf16 fused into staging
  gemm_cas<0><<<dim3(256, 6), 256, 0, stream>>>(x, casb, vv, nullptr, nullptr, 0.f);
  // Z = softshrink-MLP(V)
  mlp_kernel<<<dim3(256, 8), 384, 0, stream>>>(vv, w1f, w2f, b1, b2, zb);
  // OUT = Z @ CAS / n_tot + X
  gemm_cas<1><<<dim3(256, 6), 256, 0, stream>>>(zb, casb, nullptr, out, x, 1.0f / 25165824.0f);
}